// Round 1
// baseline (107.303 us; speedup 1.0000x reference)
//
#include <hip/hip_runtime.h>

#define NQ 10
#define NL 4
#define DIM 1024          // 2^NQ
#define BLK 512           // one pair per thread per gate

// Composed inverse permutation of the CNOT ring (control q -> target q+1 for
// q=0..8, then control=q9 -> target=q0). For a state update s'[e] = s[src(e)],
// src = sigma_0 ∘ sigma_1 ∘ ... ∘ sigma_8 ∘ sigma_wrap (each sigma involutive).
// Qubit q lives at bit position (9-q) of the basis index (qubit 0 = MSB).
__device__ __forceinline__ int cnot_src(int e) {
    // sigma_wrap: control bit0 (qubit 9), target bit9 (qubit 0)
    e ^= (e & 1) << 9;
    // sigma_q for q = 8 .. 0: control bit (9-q), target bit (8-q)
#pragma unroll
    for (int q = 8; q >= 0; --q) {
        const int cp = 9 - q;
        const int tp = 8 - q;
        e ^= ((e >> cp) & 1) << tp;
    }
    return e;
}

__global__ __launch_bounds__(BLK) void qnn_kernel(const float* __restrict__ x,
                                                  const float* __restrict__ w,
                                                  float* __restrict__ out) {
    __shared__ float2 s[DIM];
    __shared__ float cx[NQ], sx[NQ];           // RX cos/sin (batch-dependent)
    __shared__ float cw[NL * NQ], sw[NL * NQ]; // RY cos/sin (shared weights)
    __shared__ float red[8][NQ];               // cross-wave reduction

    const int tid = threadIdx.x;
    const int b   = blockIdx.x;

    // ---- init |0...0> and the angle tables ----
    s[tid]       = make_float2(0.f, 0.f);
    s[tid + BLK] = make_float2(0.f, 0.f);
    if (tid == 0) s[0] = make_float2(1.f, 0.f);

    if (tid < NQ) {
        const float a = 0.5f * x[b * NQ + tid];
        cx[tid] = cosf(a);
        sx[tid] = sinf(a);
    } else if (tid < NQ + NL * NQ) {
        const float a = 0.5f * w[tid - NQ];
        cw[tid - NQ] = cosf(a);
        sw[tid - NQ] = sinf(a);
    }
    __syncthreads();

    // ---- RX angle embedding: mat = [[c, -i s],[-i s, c]] ----
#pragma unroll
    for (int q = 0; q < NQ; ++q) {
        const int p  = 9 - q;        // bit position / log2(stride)
        const int S  = 1 << p;
        const int i0 = ((tid >> p) << (p + 1)) | (tid & (S - 1));
        const int i1 = i0 | S;
        const float2 a0 = s[i0];
        const float2 a1 = s[i1];
        const float c = cx[q], v = sx[q];
        s[i0] = make_float2(c * a0.x + v * a1.y, c * a0.y - v * a1.x);
        s[i1] = make_float2(v * a0.y + c * a1.x, -v * a0.x + c * a1.y);
        __syncthreads();
    }

    // ---- entangler layers: RY per qubit + CNOT ring ----
#pragma unroll
    for (int l = 0; l < NL; ++l) {
#pragma unroll
        for (int q = 0; q < NQ; ++q) {
            const int p  = 9 - q;
            const int S  = 1 << p;
            const int i0 = ((tid >> p) << (p + 1)) | (tid & (S - 1));
            const int i1 = i0 | S;
            const float2 a0 = s[i0];
            const float2 a1 = s[i1];
            const float c = cw[l * NQ + q], v = sw[l * NQ + q];
            s[i0] = make_float2(c * a0.x - v * a1.x, c * a0.y - v * a1.y);
            s[i1] = make_float2(v * a0.x + c * a1.x, v * a0.y + c * a1.y);
            __syncthreads();
        }
        // CNOT ring as one composed permutation (gather)
        const int e0 = tid, e1 = tid + BLK;
        const float2 v0 = s[cnot_src(e0)];
        const float2 v1 = s[cnot_src(e1)];
        __syncthreads();   // all reads done before overwrite
        s[e0] = v0;
        s[e1] = v1;
        __syncthreads();
    }

    // ---- PauliZ expectations: sum_d |s[d]|^2 * sign(d, q) ----
    const float2 a0 = s[tid];
    const float2 a1 = s[tid + BLK];
    const float p0 = a0.x * a0.x + a0.y * a0.y;
    const float p1 = a1.x * a1.x + a1.y * a1.y;
    const float ps = p0 + p1;   // bit9 differs only for qubit 0
    const float pd = p0 - p1;

    float acc[NQ];
    acc[0] = pd;                       // tid has bit9=0 -> sign +1; tid+512 -> -1
#pragma unroll
    for (int q = 1; q < NQ; ++q) {
        acc[q] = (((tid >> (9 - q)) & 1) ? -ps : ps);
    }

    // wave64 reduce, then cross-wave via LDS
#pragma unroll
    for (int q = 0; q < NQ; ++q) {
        float v = acc[q];
#pragma unroll
        for (int off = 32; off > 0; off >>= 1) v += __shfl_down(v, off);
        if ((tid & 63) == 0) red[tid >> 6][q] = v;
    }
    __syncthreads();
    if (tid < NQ) {
        float t = 0.f;
#pragma unroll
        for (int wv = 0; wv < 8; ++wv) t += red[wv][tid];
        out[b * NQ + tid] = t;
    }
}

extern "C" void kernel_launch(void* const* d_in, const int* in_sizes, int n_in,
                              void* d_out, int out_size, void* d_ws, size_t ws_size,
                              hipStream_t stream) {
    const float* x = (const float*)d_in[0];   // [2048, 10]
    const float* w = (const float*)d_in[1];   // [40]
    float* out = (float*)d_out;               // [2048, 10]
    const int B = in_sizes[0] / NQ;           // 2048
    qnn_kernel<<<B, BLK, 0, stream>>>(x, w, out);
}

// Round 4
// 80.615 us; speedup vs baseline: 1.3311x; 1.3311x over previous
//
#include <hip/hip_runtime.h>

#define NQ 10
#define NL 4

// Statevector layout: basis index e in [0,1024), qubit q lives at bit (9-q)
// (qubit 0 = MSB, matching the reference's reshape order).
//   lane  = e & 63   (bits 5..0  = qubits 4..9)
//   reg r = e >> 6   (bits 9..6  = qubits 0..3), float2 v[16] per lane.

__device__ __forceinline__ float2 shflx(float2 v, int m) {
    return make_float2(__shfl_xor(v.x, m), __shfl_xor(v.y, m));
}
__device__ __forceinline__ float2 shfll(float2 v, int sl) {
    return make_float2(__shfl(v.x, sl), __shfl(v.y, sl));
}

__global__ __launch_bounds__(256) void qnn_kernel(const float* __restrict__ x,
                                                  const float* __restrict__ w,
                                                  float* __restrict__ out,
                                                  int B) {
    const int lane = threadIdx.x & 63;
    const int b = blockIdx.x * 4 + (threadIdx.x >> 6);
    if (b >= B) return;

    // ---- per-lane angle tables (lanes 0..9: RX, lanes 0..39: RY weights) ----
    float cxv = 1.f, sxv = 0.f, cwv = 1.f, swv = 0.f;
    if (lane < NQ) {
        const float a = 0.5f * x[b * NQ + lane];
        cxv = cosf(a); sxv = sinf(a);
    }
    if (lane < NL * NQ) {
        const float a = 0.5f * w[lane];
        cwv = cosf(a); swv = sinf(a);
    }

    // broadcast RX cos/sin for all 10 qubits (v_readlane -> SGPR)
    float cq[NQ], sq[NQ];
#pragma unroll
    for (int q = 0; q < NQ; ++q) { cq[q] = __shfl(cxv, q); sq[q] = __shfl(sxv, q); }

    // ---- direct product-state construction after the RX embedding ----
    // amp(e) = [prod over qubits: bit==0 ? c_q : s_q] * (-i)^popcount(e)
    float ml = 1.f;
#pragma unroll
    for (int p = 0; p < 6; ++p) {          // lane bits: bit p = qubit 9-p
        ml *= ((lane >> p) & 1) ? sq[9 - p] : cq[9 - p];
    }
    const int kl = __popc(lane);
    const float cph = (kl & 1) ? 0.f : ((kl & 2) ? -1.f : 1.f);  // Re (-i)^kl
    const float sph = (kl & 1) ? ((kl & 2) ? 1.f : -1.f) : 0.f;  // Im (-i)^kl

    // register-bit factor products: rb0 = qubit 3, rb1 = q2, rb2 = q1, rb3 = q0
    float m01[4], m23[4];
#pragma unroll
    for (int j = 0; j < 4; ++j) {
        m01[j] = ((j & 1) ? sq[3] : cq[3]) * ((j & 2) ? sq[2] : cq[2]);
        m23[j] = ((j & 1) ? sq[1] : cq[1]) * ((j & 2) ? sq[0] : cq[0]);
    }

    float2 v[16];
#pragma unroll
    for (int r = 0; r < 16; ++r) {
        const float M = ml * m01[r & 3] * m23[r >> 2];
        const int kr = ((r & 1) + ((r >> 1) & 1) + ((r >> 2) & 1) + ((r >> 3) & 1)) & 3;
        float re, im;
        if      (kr == 0) { re = cph;  im = sph;  }
        else if (kr == 1) { re = sph;  im = -cph; }
        else if (kr == 2) { re = -cph; im = -sph; }
        else              { re = -sph; im = cph;  }
        v[r] = make_float2(M * re, M * im);
    }

    // composed source lane for the q=4..8 CNOT chain (constant across layers)
    int t = lane;
    t ^= ((t >> 1) & 1) << 0;   // sigma_{q=8}: ctrl bit1 -> tgt bit0
    t ^= ((t >> 2) & 1) << 1;   // q=7
    t ^= ((t >> 3) & 1) << 2;   // q=6
    t ^= ((t >> 4) & 1) << 3;   // q=5
    t ^= ((t >> 5) & 1) << 4;   // q=4
    const int srcl = t;
    const bool wrapctl = (lane & 1);   // wrap CNOT: ctrl = bit0 (qubit 9)

    // ---- entangler layers ----
#pragma unroll
    for (int l = 0; l < NL; ++l) {
        // RY on every qubit (shared weights, broadcast via readlane)
#pragma unroll
        for (int q = 0; q < NQ; ++q) {
            const float c = __shfl(cwv, l * NQ + q);
            const float s = __shfl(swv, l * NQ + q);
            if (q < 4) {
                // register-local: pairs differ in reg bit rb = 3-q
                const int m = 1 << (3 - q);
#pragma unroll
                for (int r = 0; r < 16; ++r) {
                    if (!(r & m)) {
                        const int r1 = r | m;
                        const float2 a0 = v[r], a1 = v[r1];
                        v[r]  = make_float2(c * a0.x - s * a1.x, c * a0.y - s * a1.y);
                        v[r1] = make_float2(s * a0.x + c * a1.x, s * a0.y + c * a1.y);
                    }
                }
            } else {
                // lane-paired: partner = lane ^ (1 << (9-q))
                const int m = 1 << (9 - q);
                const float ss = ((lane >> (9 - q)) & 1) ? s : -s;
#pragma unroll
                for (int r = 0; r < 16; ++r) {
                    const float2 o = shflx(v[r], m);
                    v[r] = make_float2(fmaf(c, v[r].x, ss * o.x),
                                       fmaf(c, v[r].y, ss * o.y));
                }
            }
        }

        // ---- CNOT ring ----
        // q=0: ctrl rb3, tgt rb2 -> swap (8,12)(9,13)(10,14)(11,15)
        { float2 tmp;
          tmp = v[8];  v[8]  = v[12]; v[12] = tmp;
          tmp = v[9];  v[9]  = v[13]; v[13] = tmp;
          tmp = v[10]; v[10] = v[14]; v[14] = tmp;
          tmp = v[11]; v[11] = v[15]; v[15] = tmp; }
        // q=1: ctrl rb2, tgt rb1 -> swap (4,6)(5,7)(12,14)(13,15)
        { float2 tmp;
          tmp = v[4];  v[4]  = v[6];  v[6]  = tmp;
          tmp = v[5];  v[5]  = v[7];  v[7]  = tmp;
          tmp = v[12]; v[12] = v[14]; v[14] = tmp;
          tmp = v[13]; v[13] = v[15]; v[15] = tmp; }
        // q=2: ctrl rb1, tgt rb0 -> swap (2,3)(6,7)(10,11)(14,15)
        { float2 tmp;
          tmp = v[2];  v[2]  = v[3];  v[3]  = tmp;
          tmp = v[6];  v[6]  = v[7];  v[7]  = tmp;
          tmp = v[10]; v[10] = v[11]; v[11] = tmp;
          tmp = v[14]; v[14] = v[15]; v[15] = tmp; }
        // q=3: ctrl rb0 (odd r), tgt lane bit5 -> cross-lane swap via shfl_xor(32)
#pragma unroll
        for (int r = 1; r < 16; r += 2) v[r] = shflx(v[r], 32);
        // q=4..8 composed lane permutation (gather from srcl)
#pragma unroll
        for (int r = 0; r < 16; ++r) v[r] = shfll(v[r], srcl);
        // wrap: ctrl lane bit0, tgt rb3 -> conditional swap v[r] <-> v[r+8]
#pragma unroll
        for (int r = 0; r < 8; ++r) {
            const float2 a = v[r], c2 = v[r + 8];
            v[r]     = wrapctl ? c2 : a;
            v[r + 8] = wrapctl ? a : c2;
        }
    }

    // ---- PauliZ expectations ----
    float p[16];
    float T = 0.f;
#pragma unroll
    for (int r = 0; r < 16; ++r) {
        p[r] = v[r].x * v[r].x + v[r].y * v[r].y;
        T += p[r];
    }
    float S0 = 0.f, S1 = 0.f, S2 = 0.f, S3 = 0.f;
#pragma unroll
    for (int r = 0; r < 16; ++r) {
        S0 += (r & 8) ? -p[r] : p[r];   // qubit 0 (rb3)
        S1 += (r & 4) ? -p[r] : p[r];   // qubit 1 (rb2)
        S2 += (r & 2) ? -p[r] : p[r];   // qubit 2 (rb1)
        S3 += (r & 1) ? -p[r] : p[r];   // qubit 3 (rb0)
    }
    float acc[NQ];
    acc[0] = S0; acc[1] = S1; acc[2] = S2; acc[3] = S3;
#pragma unroll
    for (int q = 4; q < NQ; ++q) {
        acc[q] = ((lane >> (9 - q)) & 1) ? -T : T;   // lane-bit qubits
    }
#pragma unroll
    for (int q = 0; q < NQ; ++q) {
#pragma unroll
        for (int off = 32; off; off >>= 1) acc[q] += __shfl_xor(acc[q], off);
    }
    if (lane == 0) {
#pragma unroll
        for (int q = 0; q < NQ; ++q) out[b * NQ + q] = acc[q];
    }
}

extern "C" void kernel_launch(void* const* d_in, const int* in_sizes, int n_in,
                              void* d_out, int out_size, void* d_ws, size_t ws_size,
                              hipStream_t stream) {
    const float* x = (const float*)d_in[0];   // [B, 10]
    const float* w = (const float*)d_in[1];   // [40]
    float* out = (float*)d_out;               // [B, 10]
    const int B = in_sizes[0] / NQ;           // 2048
    qnn_kernel<<<(B + 3) / 4, 256, 0, stream>>>(x, w, out, B);
}

// Round 10
// 71.474 us; speedup vs baseline: 1.5013x; 1.1279x over previous
//
#include <hip/hip_runtime.h>

#define NQ 10
#define NL 4

// Statevector layout: basis index e in [0,1024), qubit q lives at bit (9-q).
//   lane  = e & 63   (bits 5..0  = qubits 4..9)
//   reg r = e >> 6   (bits 9..6  = qubits 0..3), float2 v[16] per lane.
//
// Cross-lane strategy — proven primitives only (permlane_swap failed twice):
//   xor1  -> DPP quad_perm [1,0,3,2] = 0xB1   (VALU)
//   xor2  -> DPP quad_perm [2,3,0,1] = 0x4E   (VALU)
//   xor4  -> ds_swizzle BitMode 0x101F        (DS)
//   xor8  -> DPP row_ror:8 = 0x128            (VALU)
//   xor16 -> ds_swizzle BitMode 0x401F        (DS)
//   xor32 -> ds_bpermute addr=(lane^32)<<2    (DS)  [== round-4's shfl_xor(32)]
//   composed CNOT gather -> ds_bpermute       (DS)

template<int CTRL>
__device__ __forceinline__ float dppf(float v) {
    const int i = __float_as_int(v);
    const int r = __builtin_amdgcn_update_dpp(i, i, CTRL, 0xF, 0xF, false);
    return __int_as_float(r);
}
template<int OFF>
__device__ __forceinline__ float swzf(float v) {
    return __int_as_float(__builtin_amdgcn_ds_swizzle(__float_as_int(v), OFF));
}
__device__ __forceinline__ float bpermf(int addr4, float v) {
    return __int_as_float(__builtin_amdgcn_ds_bpermute(addr4, __float_as_int(v)));
}
__device__ __forceinline__ float rdlane(float v, int l) {
    return __int_as_float(__builtin_amdgcn_readlane(__float_as_int(v), l));
}

__global__ __launch_bounds__(256) void qnn_kernel(const float* __restrict__ x,
                                                  const float* __restrict__ w,
                                                  float* __restrict__ out,
                                                  int B) {
    const int lane = threadIdx.x & 63;
    const int b = blockIdx.x * 4 + (threadIdx.x >> 6);
    if (b >= B) return;

    // ---- per-lane angle tables (lanes 0..9: RX, lanes 0..39: RY weights) ----
    float cxv = 1.f, sxv = 0.f, cwv = 1.f, swv = 0.f;
    if (lane < NQ) {
        const float a = 0.5f * x[b * NQ + lane];
        cxv = cosf(a); sxv = sinf(a);
    }
    if (lane < NL * NQ) {
        const float a = 0.5f * w[lane];
        cwv = cosf(a); swv = sinf(a);
    }

    // broadcast RX cos/sin for all 10 qubits (v_readlane -> SGPR)
    float cq[NQ], sq[NQ];
#pragma unroll
    for (int q = 0; q < NQ; ++q) { cq[q] = rdlane(cxv, q); sq[q] = rdlane(sxv, q); }

    // ---- direct product-state construction after the RX embedding ----
    // amp(e) = [prod over qubits: bit==0 ? c_q : s_q] * (-i)^popcount(e)
    float ml = 1.f;
#pragma unroll
    for (int p = 0; p < 6; ++p) {          // lane bits: bit p = qubit 9-p
        ml *= ((lane >> p) & 1) ? sq[9 - p] : cq[9 - p];
    }
    const int kl = __popc(lane);
    const float cph = (kl & 1) ? 0.f : ((kl & 2) ? -1.f : 1.f);  // Re (-i)^kl
    const float sph = (kl & 1) ? ((kl & 2) ? 1.f : -1.f) : 0.f;  // Im (-i)^kl

    // register-bit factor products: rb0 = qubit 3, rb1 = q2, rb2 = q1, rb3 = q0
    float m01[4], m23[4];
#pragma unroll
    for (int j = 0; j < 4; ++j) {
        m01[j] = ((j & 1) ? sq[3] : cq[3]) * ((j & 2) ? sq[2] : cq[2]);
        m23[j] = ((j & 1) ? sq[1] : cq[1]) * ((j & 2) ? sq[0] : cq[0]);
    }

    float2 v[16];
#pragma unroll
    for (int r = 0; r < 16; ++r) {
        const float M = ml * m01[r & 3] * m23[r >> 2];
        const int kr = ((r & 1) + ((r >> 1) & 1) + ((r >> 2) & 1) + ((r >> 3) & 1)) & 3;
        float re, im;
        if      (kr == 0) { re = cph;  im = sph;  }
        else if (kr == 1) { re = sph;  im = -cph; }
        else if (kr == 2) { re = -cph; im = -sph; }
        else              { re = -sph; im = cph;  }
        v[r] = make_float2(M * re, M * im);
    }

    // composed source lane for the q=4..8 CNOT chain (constant across layers);
    // sigma_{q=3} (ctrl rb0, tgt lane bit5) folded in: odd regs gather from srcl^32.
    int t = lane;
    t ^= ((t >> 1) & 1) << 0;   // sigma_{q=8}: ctrl bit1 -> tgt bit0
    t ^= ((t >> 2) & 1) << 1;   // q=7
    t ^= ((t >> 3) & 1) << 2;   // q=6
    t ^= ((t >> 4) & 1) << 3;   // q=5
    t ^= ((t >> 5) & 1) << 4;   // q=4
    const int ga4 = t << 2;            // bpermute byte addr, even regs
    const int gb4 = (t ^ 32) << 2;     // odd regs (sigma_3 folded)
    const int a32 = (lane ^ 32) << 2;  // xor32 partner bpermute addr
    const bool wrapctl = (lane & 1);   // wrap CNOT: ctrl = bit0 (qubit 9)

    // ---- entangler layers ----
#pragma unroll
    for (int l = 0; l < NL; ++l) {
        // q = 0..3: register-local RY
#pragma unroll
        for (int q = 0; q < 4; ++q) {
            const float c = rdlane(cwv, l * NQ + q);
            const float s = rdlane(swv, l * NQ + q);
            const int m = 1 << (3 - q);
#pragma unroll
            for (int r = 0; r < 16; ++r) {
                if (!(r & m)) {
                    const int r1 = r | m;
                    const float2 a0 = v[r], a1 = v[r1];
                    v[r]  = make_float2(c * a0.x - s * a1.x, c * a0.y - s * a1.y);
                    v[r1] = make_float2(s * a0.x + c * a1.x, s * a0.y + c * a1.y);
                }
            }
        }
        // q = 4 (lane xor32): ds_bpermute partner exchange
        {
            const float c = rdlane(cwv, l * NQ + 4);
            const float s = rdlane(swv, l * NQ + 4);
            const float ss = (lane & 32) ? s : -s;
#pragma unroll
            for (int r = 0; r < 16; ++r) {
                const float ox = bpermf(a32, v[r].x);
                const float oy = bpermf(a32, v[r].y);
                v[r].x = fmaf(c, v[r].x, ss * ox);
                v[r].y = fmaf(c, v[r].y, ss * oy);
            }
        }
        // q = 5 (lane xor16): ds_swizzle 0x401F
        {
            const float c = rdlane(cwv, l * NQ + 5);
            const float s = rdlane(swv, l * NQ + 5);
            const float ss = (lane & 16) ? s : -s;
#pragma unroll
            for (int r = 0; r < 16; ++r) {
                const float ox = swzf<0x401F>(v[r].x);
                const float oy = swzf<0x401F>(v[r].y);
                v[r].x = fmaf(c, v[r].x, ss * ox);
                v[r].y = fmaf(c, v[r].y, ss * oy);
            }
        }
        // q = 6 (xor8): DPP row_ror:8
        {
            const float c = rdlane(cwv, l * NQ + 6);
            const float s = rdlane(swv, l * NQ + 6);
            const float ss = (lane & 8) ? s : -s;
#pragma unroll
            for (int r = 0; r < 16; ++r) {
                const float ox = dppf<0x128>(v[r].x);
                const float oy = dppf<0x128>(v[r].y);
                v[r].x = fmaf(c, v[r].x, ss * ox);
                v[r].y = fmaf(c, v[r].y, ss * oy);
            }
        }
        // q = 7 (xor4): ds_swizzle 0x101F
        {
            const float c = rdlane(cwv, l * NQ + 7);
            const float s = rdlane(swv, l * NQ + 7);
            const float ss = (lane & 4) ? s : -s;
#pragma unroll
            for (int r = 0; r < 16; ++r) {
                const float ox = swzf<0x101F>(v[r].x);
                const float oy = swzf<0x101F>(v[r].y);
                v[r].x = fmaf(c, v[r].x, ss * ox);
                v[r].y = fmaf(c, v[r].y, ss * oy);
            }
        }
        // q = 8 (xor2): DPP quad_perm [2,3,0,1]
        {
            const float c = rdlane(cwv, l * NQ + 8);
            const float s = rdlane(swv, l * NQ + 8);
            const float ss = (lane & 2) ? s : -s;
#pragma unroll
            for (int r = 0; r < 16; ++r) {
                const float ox = dppf<0x4E>(v[r].x);
                const float oy = dppf<0x4E>(v[r].y);
                v[r].x = fmaf(c, v[r].x, ss * ox);
                v[r].y = fmaf(c, v[r].y, ss * oy);
            }
        }
        // q = 9 (xor1): DPP quad_perm [1,0,3,2]
        {
            const float c = rdlane(cwv, l * NQ + 9);
            const float s = rdlane(swv, l * NQ + 9);
            const float ss = (lane & 1) ? s : -s;
#pragma unroll
            for (int r = 0; r < 16; ++r) {
                const float ox = dppf<0xB1>(v[r].x);
                const float oy = dppf<0xB1>(v[r].y);
                v[r].x = fmaf(c, v[r].x, ss * ox);
                v[r].y = fmaf(c, v[r].y, ss * oy);
            }
        }

        // ---- CNOT ring ----
        // q=0,1,2: register renames
        { float2 tmp;
          tmp = v[8];  v[8]  = v[12]; v[12] = tmp;
          tmp = v[9];  v[9]  = v[13]; v[13] = tmp;
          tmp = v[10]; v[10] = v[14]; v[14] = tmp;
          tmp = v[11]; v[11] = v[15]; v[15] = tmp; }
        { float2 tmp;
          tmp = v[4];  v[4]  = v[6];  v[6]  = tmp;
          tmp = v[5];  v[5]  = v[7];  v[7]  = tmp;
          tmp = v[12]; v[12] = v[14]; v[14] = tmp;
          tmp = v[13]; v[13] = v[15]; v[15] = tmp; }
        { float2 tmp;
          tmp = v[2];  v[2]  = v[3];  v[3]  = tmp;
          tmp = v[6];  v[6]  = v[7];  v[7]  = tmp;
          tmp = v[10]; v[10] = v[11]; v[11] = tmp;
          tmp = v[14]; v[14] = v[15]; v[15] = tmp; }
        // q=3..8 fused: gather from g(lane) (even r) / g(lane)^32 (odd r)
#pragma unroll
        for (int r = 0; r < 16; ++r) {
            const int a4 = (r & 1) ? gb4 : ga4;
            v[r].x = bpermf(a4, v[r].x);
            v[r].y = bpermf(a4, v[r].y);
        }
        // wrap: ctrl lane bit0, tgt rb3 -> conditional swap v[r] <-> v[r+8]
#pragma unroll
        for (int r = 0; r < 8; ++r) {
            const float2 a = v[r], c2 = v[r + 8];
            v[r]     = wrapctl ? c2 : a;
            v[r + 8] = wrapctl ? a : c2;
        }
    }

    // ---- PauliZ expectations ----
    float p[16];
    float T = 0.f;
#pragma unroll
    for (int r = 0; r < 16; ++r) {
        p[r] = v[r].x * v[r].x + v[r].y * v[r].y;
        T += p[r];
    }
    float S0 = 0.f, S1 = 0.f, S2 = 0.f, S3 = 0.f;
#pragma unroll
    for (int r = 0; r < 16; ++r) {
        S0 += (r & 8) ? -p[r] : p[r];   // qubit 0 (rb3)
        S1 += (r & 4) ? -p[r] : p[r];   // qubit 1 (rb2)
        S2 += (r & 2) ? -p[r] : p[r];   // qubit 2 (rb1)
        S3 += (r & 1) ? -p[r] : p[r];   // qubit 3 (rb0)
    }
    float acc[NQ];
    acc[0] = S0; acc[1] = S1; acc[2] = S2; acc[3] = S3;
#pragma unroll
    for (int q = 4; q < NQ; ++q) {
        acc[q] = ((lane >> (9 - q)) & 1) ? -T : T;   // lane-bit qubits
    }

    // 64-lane reduce per qubit: bperm (xor32) + swizzle/DPP butterfly
#pragma unroll
    for (int q = 0; q < NQ; ++q) {
        float a = acc[q];
        a += bpermf(a32, a);
        a += swzf<0x401F>(a);
        a += dppf<0x128>(a);
        a += swzf<0x101F>(a);
        a += dppf<0x4E>(a);
        a += dppf<0xB1>(a);
        acc[q] = a;
    }
    if (lane == 0) {
#pragma unroll
        for (int q = 0; q < NQ; ++q) out[b * NQ + q] = acc[q];
    }
}

extern "C" void kernel_launch(void* const* d_in, const int* in_sizes, int n_in,
                              void* d_out, int out_size, void* d_ws, size_t ws_size,
                              hipStream_t stream) {
    const float* x = (const float*)d_in[0];   // [B, 10]
    const float* w = (const float*)d_in[1];   // [40]
    float* out = (float*)d_out;               // [B, 10]
    const int B = in_sizes[0] / NQ;           // 2048
    qnn_kernel<<<(B + 3) / 4, 256, 0, stream>>>(x, w, out, B);
}

// Round 11
// 66.752 us; speedup vs baseline: 1.6075x; 1.0707x over previous
//
#include <hip/hip_runtime.h>

#define NQ 10

// Statevector layout: basis index e in [0,1024), qubit q lives at bit (9-q).
//   lane  = e & 63   (bits 5..0  = qubits 4..9)
//   reg r = e >> 6   (bits 9..6  = qubits 0..3), v2f v[16] = (re,im) per lane.
//
// Circuit restructured (algebra, not new primitives):
//   RX embedding + layer-0 RY  -> direct complex product-state construction
//   loop l=0..2: CNOT ring l ; RY sweep layer l+1
//   CNOT ring 3 -> folded into measurement signs (prefix-parity masks)
//
// Cross-lane primitives: exactly the round-10 PASSING set.
//   xor1 -> DPP quad_perm 0xB1, xor2 -> 0x4E, xor8 -> row_ror:8 (0x128)
//   xor4 -> ds_swizzle 0x101F, xor16 -> ds_swizzle 0x401F
//   xor32 + composed CNOT gather -> ds_bpermute

typedef float v2f __attribute__((ext_vector_type(2)));

template<int CTRL>
__device__ __forceinline__ float dppf(float v) {
    const int i = __float_as_int(v);
    const int r = __builtin_amdgcn_update_dpp(i, i, CTRL, 0xF, 0xF, false);
    return __int_as_float(r);
}
template<int OFF>
__device__ __forceinline__ float swzf(float v) {
    return __int_as_float(__builtin_amdgcn_ds_swizzle(__float_as_int(v), OFF));
}
__device__ __forceinline__ float bpermf(int addr4, float v) {
    return __int_as_float(__builtin_amdgcn_ds_bpermute(addr4, __float_as_int(v)));
}
__device__ __forceinline__ float rdlane(float v, int l) {
    return __int_as_float(__builtin_amdgcn_readlane(__float_as_int(v), l));
}
__device__ __forceinline__ v2f splat(float a) { v2f r; r.x = a; r.y = a; return r; }
__device__ __forceinline__ v2f cmul(v2f a, v2f b) {   // complex multiply
    v2f r;
    r.x = a.x * b.x - a.y * b.y;
    r.y = a.x * b.y + a.y * b.x;
    return r;
}

__global__ __launch_bounds__(256) void qnn_kernel(const float* __restrict__ x,
                                                  const float* __restrict__ w,
                                                  float* __restrict__ out,
                                                  int B) {
    const int lane = threadIdx.x & 63;
    const int b = blockIdx.x * 4 + (threadIdx.x >> 6);
    if (b >= B) return;

    // ---- angle tables: lanes 0..9 RX(x), lanes 0..39 RY weights ----
    float cxv = 1.f, sxv = 0.f, cwv = 1.f, swv = 0.f;
    if (lane < NQ) {
        const float a = 0.5f * x[b * NQ + lane];
        cxv = cosf(a); sxv = sinf(a);
    }
    if (lane < 4 * NQ) {
        const float a = 0.5f * w[lane];
        cwv = cosf(a); swv = sinf(a);
    }

    // ---- per-qubit 2-vectors after RX(x_q) then layer-0 RY(w0_q) ----
    // RX|0> = (c, -i s);  RY = [[ch,-sh],[sh,ch]]
    // u0 = (ch*c, sh*s), u1 = (sh*c, -ch*s)
    v2f u0[NQ], u1[NQ];
#pragma unroll
    for (int q = 0; q < NQ; ++q) {
        const float c  = rdlane(cxv, q), s  = rdlane(sxv, q);
        const float ch = rdlane(cwv, q), sh = rdlane(swv, q);
        u0[q].x = ch * c;  u0[q].y = sh * s;
        u1[q].x = sh * c;  u1[q].y = -ch * s;
    }

    // ---- product state: amp(e) = prod_q u_q[bit_q(e)] ----
    v2f ml = (lane & 1) ? u1[9] : u0[9];           // lane bit p = qubit 9-p
#pragma unroll
    for (int p = 1; p < 6; ++p) {
        const v2f f = ((lane >> p) & 1) ? u1[9 - p] : u0[9 - p];
        ml = cmul(ml, f);
    }
    v2f m01[4], m23[4], tml[4];
#pragma unroll
    for (int j = 0; j < 4; ++j) {                  // r bit0=qubit3, bit1=qubit2
        m01[j] = cmul((j & 1) ? u1[3] : u0[3], (j & 2) ? u1[2] : u0[2]);
        m23[j] = cmul((j & 1) ? u1[1] : u0[1], (j & 2) ? u1[0] : u0[0]);
    }
#pragma unroll
    for (int j = 0; j < 4; ++j) tml[j] = cmul(ml, m01[j]);

    v2f v[16];
#pragma unroll
    for (int r = 0; r < 16; ++r) v[r] = cmul(tml[r & 3], m23[r >> 2]);

    // composed source lane for the q=4..8 CNOT chain; sigma_{q=3} folded:
    // odd regs gather from srcl^32.
    int t = lane;
    t ^= ((t >> 1) & 1) << 0;   // sigma_{q=8}
    t ^= ((t >> 2) & 1) << 1;   // q=7
    t ^= ((t >> 3) & 1) << 2;   // q=6
    t ^= ((t >> 4) & 1) << 3;   // q=5
    t ^= ((t >> 5) & 1) << 4;   // q=4
    const int ga4 = t << 2;            // bpermute byte addr, even regs
    const int gb4 = (t ^ 32) << 2;     // odd regs
    const int a32 = (lane ^ 32) << 2;  // xor32 partner addr
    const bool wrapctl = (lane & 1);   // wrap CNOT ctrl = qubit 9

    // ---- 3x { CNOT ring ; RY sweep(layer l+1) } ----
#pragma unroll
    for (int l = 0; l < 3; ++l) {
        // -- CNOT ring --
        { v2f tmp;
          tmp = v[8];  v[8]  = v[12]; v[12] = tmp;   // q=0: ctrl rb3, tgt rb2
          tmp = v[9];  v[9]  = v[13]; v[13] = tmp;
          tmp = v[10]; v[10] = v[14]; v[14] = tmp;
          tmp = v[11]; v[11] = v[15]; v[15] = tmp; }
        { v2f tmp;
          tmp = v[4];  v[4]  = v[6];  v[6]  = tmp;   // q=1: ctrl rb2, tgt rb1
          tmp = v[5];  v[5]  = v[7];  v[7]  = tmp;
          tmp = v[12]; v[12] = v[14]; v[14] = tmp;
          tmp = v[13]; v[13] = v[15]; v[15] = tmp; }
        { v2f tmp;
          tmp = v[2];  v[2]  = v[3];  v[3]  = tmp;   // q=2: ctrl rb1, tgt rb0
          tmp = v[6];  v[6]  = v[7];  v[7]  = tmp;
          tmp = v[10]; v[10] = v[11]; v[11] = tmp;
          tmp = v[14]; v[14] = v[15]; v[15] = tmp; }
#pragma unroll
        for (int r = 0; r < 16; ++r) {               // q=3..8 fused gather
            const int a4 = (r & 1) ? gb4 : ga4;
            v[r].x = bpermf(a4, v[r].x);
            v[r].y = bpermf(a4, v[r].y);
        }
#pragma unroll
        for (int r = 0; r < 8; ++r) {                // wrap: ctrl lane bit0, tgt rb3
            const v2f a = v[r], c2 = v[r + 8];
            v[r]     = wrapctl ? c2 : a;
            v[r + 8] = wrapctl ? a : c2;
        }

        // -- RY sweep, layer l+1 --
        const int base = (l + 1) * NQ;
        // q = 0..3: register-local
#pragma unroll
        for (int q = 0; q < 4; ++q) {
            const v2f C = splat(rdlane(cwv, base + q));
            const v2f S = splat(rdlane(swv, base + q));
            const int m = 1 << (3 - q);
#pragma unroll
            for (int r = 0; r < 16; ++r) {
                if (!(r & m)) {
                    const int r1 = r | m;
                    const v2f a0 = v[r], a1 = v[r1];
                    v[r]  = C * a0 - S * a1;
                    v[r1] = S * a0 + C * a1;
                }
            }
        }
        // q = 4 (xor32): ds_bpermute
        {
            const float c = rdlane(cwv, base + 4);
            const float s = rdlane(swv, base + 4);
            const v2f C = splat(c);
            const v2f SS = splat((lane & 32) ? s : -s);
#pragma unroll
            for (int r = 0; r < 16; ++r) {
                v2f o; o.x = bpermf(a32, v[r].x); o.y = bpermf(a32, v[r].y);
                v[r] = C * v[r] + SS * o;
            }
        }
        // q = 5 (xor16): ds_swizzle 0x401F
        {
            const float c = rdlane(cwv, base + 5);
            const float s = rdlane(swv, base + 5);
            const v2f C = splat(c);
            const v2f SS = splat((lane & 16) ? s : -s);
#pragma unroll
            for (int r = 0; r < 16; ++r) {
                v2f o; o.x = swzf<0x401F>(v[r].x); o.y = swzf<0x401F>(v[r].y);
                v[r] = C * v[r] + SS * o;
            }
        }
        // q = 6 (xor8): DPP row_ror:8
        {
            const float c = rdlane(cwv, base + 6);
            const float s = rdlane(swv, base + 6);
            const v2f C = splat(c);
            const v2f SS = splat((lane & 8) ? s : -s);
#pragma unroll
            for (int r = 0; r < 16; ++r) {
                v2f o; o.x = dppf<0x128>(v[r].x); o.y = dppf<0x128>(v[r].y);
                v[r] = C * v[r] + SS * o;
            }
        }
        // q = 7 (xor4): ds_swizzle 0x101F
        {
            const float c = rdlane(cwv, base + 7);
            const float s = rdlane(swv, base + 7);
            const v2f C = splat(c);
            const v2f SS = splat((lane & 4) ? s : -s);
#pragma unroll
            for (int r = 0; r < 16; ++r) {
                v2f o; o.x = swzf<0x101F>(v[r].x); o.y = swzf<0x101F>(v[r].y);
                v[r] = C * v[r] + SS * o;
            }
        }
        // q = 8 (xor2): DPP quad_perm [2,3,0,1]
        {
            const float c = rdlane(cwv, base + 8);
            const float s = rdlane(swv, base + 8);
            const v2f C = splat(c);
            const v2f SS = splat((lane & 2) ? s : -s);
#pragma unroll
            for (int r = 0; r < 16; ++r) {
                v2f o; o.x = dppf<0x4E>(v[r].x); o.y = dppf<0x4E>(v[r].y);
                v[r] = C * v[r] + SS * o;
            }
        }
        // q = 9 (xor1): DPP quad_perm [1,0,3,2]
        {
            const float c = rdlane(cwv, base + 9);
            const float s = rdlane(swv, base + 9);
            const v2f C = splat(c);
            const v2f SS = splat((lane & 1) ? s : -s);
#pragma unroll
            for (int r = 0; r < 16; ++r) {
                v2f o; o.x = dppf<0xB1>(v[r].x); o.y = dppf<0xB1>(v[r].y);
                v[r] = C * v[r] + SS * o;
            }
        }
    }

    // ---- measurement with ring-3 folded into signs ----
    // P(e): bit_k' = b0^...^bk (k>=1), bit_0' = b1^...^b9.
    // Z_0: parity(qubits 1..9) = parity(r&7) ^ parity(lane)
    // Z_q (1..3): parity(qubits 0..q) = parity(r & mask), mask = 12,14,15
    // Z_q (4..9): parity(r) ^ parity(lane & Mq), Mq = 0x20,0x30,0x38,0x3C,0x3E,0x3F
    float p[16];
#pragma unroll
    for (int r = 0; r < 16; ++r) p[r] = v[r].x * v[r].x + v[r].y * v[r].y;

    float S15 = 0.f, S7 = 0.f, S12 = 0.f, S14 = 0.f;
#pragma unroll
    for (int r = 0; r < 16; ++r) {
        const float pr = p[r];
        S15 += (__popc(r) & 1)      ? -pr : pr;
        S7  += (__popc(r & 7) & 1)  ? -pr : pr;
        S12 += (__popc(r & 12) & 1) ? -pr : pr;
        S14 += (__popc(r & 14) & 1) ? -pr : pr;
    }

    const float gAll = (__popc(lane) & 1) ? -1.f : 1.f;          // mask 0x3F
    float acc[NQ];
    acc[0] = gAll * S7;
    acc[1] = S12;
    acc[2] = S14;
    acc[3] = S15;
    acc[4] = ((lane >> 5) & 1) ? -S15 : S15;                      // 0x20
    acc[5] = (__popc(lane & 0x30) & 1) ? -S15 : S15;
    acc[6] = (__popc(lane & 0x38) & 1) ? -S15 : S15;
    acc[7] = (__popc(lane & 0x3C) & 1) ? -S15 : S15;
    acc[8] = (__popc(lane & 0x3E) & 1) ? -S15 : S15;
    acc[9] = gAll * S15;

    // 64-lane reduce per qubit: bperm (xor32) + swizzle/DPP butterfly
#pragma unroll
    for (int q = 0; q < NQ; ++q) {
        float a = acc[q];
        a += bpermf(a32, a);
        a += swzf<0x401F>(a);
        a += dppf<0x128>(a);
        a += swzf<0x101F>(a);
        a += dppf<0x4E>(a);
        a += dppf<0xB1>(a);
        acc[q] = a;
    }
    if (lane == 0) {
#pragma unroll
        for (int q = 0; q < NQ; ++q) out[b * NQ + q] = acc[q];
    }
}

extern "C" void kernel_launch(void* const* d_in, const int* in_sizes, int n_in,
                              void* d_out, int out_size, void* d_ws, size_t ws_size,
                              hipStream_t stream) {
    const float* x = (const float*)d_in[0];   // [B, 10]
    const float* w = (const float*)d_in[1];   // [40]
    float* out = (float*)d_out;               // [B, 10]
    const int B = in_sizes[0] / NQ;           // 2048
    qnn_kernel<<<(B + 3) / 4, 256, 0, stream>>>(x, w, out, B);
}